// Round 1
// baseline (291.911 us; speedup 1.0000x reference)
//
#include <hip/hip_runtime.h>

// Problem constants (from reference setup_inputs)
#define B_  8192
#define C_  64
#define K_  256
#define D_  64
#define NB_ 32            // B_ / 256 : b-blocks per channel
#define BN_EPS 1e-5

// ---------------------------------------------------------------------------
// Kernel 1: fused scoring.
// grid = (NB_, C_), block = 256. Thread t of block (i, c) owns row b = i*256+t
// of channel c. Computes all K=256 dot products r[b,c,k], tracks max/argmax
// (and min/argmin for negative-gamma robustness), accumulates sum and sum-sq
// for the channel's BN statistics (block-reduced into per-block partials).
// Raw max -> d_out mse slot (finalized by kernel 3); argmax (as float) ->
// d_out codes slot.
// ---------------------------------------------------------------------------
__global__ __launch_bounds__(256) void dpq_score(
    const float* __restrict__ x,        // (B, C, D)
    const float* __restrict__ cent,     // (C, K, D)
    float* __restrict__ out,            // d_out: [codes B*C][mse B*C][centroids]
    float* __restrict__ part_sum,       // (C, NB_)
    float* __restrict__ part_sq,        // (C, NB_)
    float* __restrict__ minv,           // (B*C) or null
    float* __restrict__ argminv)        // (B*C) or null
{
    const int c = blockIdx.y;
    const int b = blockIdx.x * 256 + threadIdx.x;

    // Load this row's input vector into registers (16 x float4 = 64 floats).
    float xv[D_];
    const float4* xr = reinterpret_cast<const float4*>(x + ((size_t)b * C_ + c) * D_);
#pragma unroll
    for (int i = 0; i < D_ / 4; ++i) {
        float4 v = xr[i];
        xv[4 * i + 0] = v.x; xv[4 * i + 1] = v.y;
        xv[4 * i + 2] = v.z; xv[4 * i + 3] = v.w;
    }

    const float* crow = cent + (size_t)c * K_ * D_;   // wave-uniform base

    float accs = 0.f, accq = 0.f;
    float best = -3.4e38f, worst = 3.4e38f;
    int bestk = 0, worstk = 0;

    for (int k = 0; k < K_; ++k) {
        const float* cr = crow + k * D_;              // uniform address -> s_load
        float r0 = 0.f, r1 = 0.f, r2 = 0.f, r3 = 0.f; // break FMA dep chain 4-way
#pragma unroll
        for (int d = 0; d < D_; d += 4) {
            r0 = fmaf(xv[d + 0], cr[d + 0], r0);
            r1 = fmaf(xv[d + 1], cr[d + 1], r1);
            r2 = fmaf(xv[d + 2], cr[d + 2], r2);
            r3 = fmaf(xv[d + 3], cr[d + 3], r3);
        }
        float r = (r0 + r1) + (r2 + r3);

        accs += r;
        accq = fmaf(r, r, accq);
        if (r > best)  { best = r;  bestk = k; }   // strict > keeps first occurrence
        if (r < worst) { worst = r; worstk = k; }
    }

    const size_t idx = (size_t)b * C_ + c;
    out[idx] = (float)bestk;                 // codes (as float; harness reads f32)
    out[(size_t)B_ * C_ + idx] = best;       // raw max, finalized by kernel 3
    if (minv) {
        minv[idx] = worst;
        argminv[idx] = (float)worstk;
    }

    // Block reduction of accs/accq -> per-block channel partials.
#pragma unroll
    for (int off = 32; off > 0; off >>= 1) {
        accs += __shfl_down(accs, off, 64);
        accq += __shfl_down(accq, off, 64);
    }
    __shared__ float ls[4], lq[4];
    const int wid  = threadIdx.x >> 6;
    const int lane = threadIdx.x & 63;
    if (lane == 0) { ls[wid] = accs; lq[wid] = accq; }
    __syncthreads();
    if (threadIdx.x == 0) {
        float s = (ls[0] + ls[1]) + (ls[2] + ls[3]);
        float q = (lq[0] + lq[1]) + (lq[2] + lq[3]);
        part_sum[c * NB_ + blockIdx.x] = s;
        part_sq [c * NB_ + blockIdx.x] = q;
    }
}

// ---------------------------------------------------------------------------
// Kernel 2: per-channel BN stats -> (scale, shift), fp64 for the final reduce.
// One block, 64 threads (one per channel).
// ---------------------------------------------------------------------------
__global__ void dpq_stats(
    const float* __restrict__ part_sum,
    const float* __restrict__ part_sq,
    const float* __restrict__ gamma,
    const float* __restrict__ beta,
    float* __restrict__ scale_out,
    float* __restrict__ shift_out)
{
    const int c = threadIdx.x;
    if (c >= C_) return;
    double s = 0.0, q = 0.0;
    for (int i = 0; i < NB_; ++i) {
        s += (double)part_sum[c * NB_ + i];
        q += (double)part_sq [c * NB_ + i];
    }
    const double n    = (double)B_ * (double)K_;
    const double mean = s / n;
    const double var  = q / n - mean * mean;      // biased, matches reference
    const double sc   = (double)gamma[c] / sqrt(var + BN_EPS);
    const double sh   = (double)beta[c] - mean * sc;
    scale_out[c] = (float)sc;
    shift_out[c] = (float)sh;
}

// ---------------------------------------------------------------------------
// Kernel 3: apply per-channel affine to the stored raw max (in-place in d_out).
// Handles negative scale (argmax of normalized == argmin of raw) if min data
// is available.
// ---------------------------------------------------------------------------
__global__ __launch_bounds__(256) void dpq_apply(
    float* __restrict__ out,
    const float* __restrict__ scale,
    const float* __restrict__ shift,
    const float* __restrict__ minv,
    const float* __restrict__ argminv)
{
    const int idx = blockIdx.x * 256 + threadIdx.x;   // over B*C, c fastest
    const int c = idx & (C_ - 1);
    const float sc = scale[c];
    const float sh = shift[c];
    if (sc >= 0.f || minv == nullptr) {
        const float raw = out[(size_t)B_ * C_ + idx];
        out[(size_t)B_ * C_ + idx] = fmaf(raw, sc, sh);
    } else {
        out[(size_t)B_ * C_ + idx] = fmaf(minv[idx], sc, sh);
        out[idx] = argminv[idx];
    }
}

// ---------------------------------------------------------------------------
extern "C" void kernel_launch(void* const* d_in, const int* in_sizes, int n_in,
                              void* d_out, int out_size, void* d_ws, size_t ws_size,
                              hipStream_t stream)
{
    const float* x     = (const float*)d_in[0];   // (B, C, D)
    const float* cent  = (const float*)d_in[1];   // (C, K, D)
    const float* gamma = (const float*)d_in[2];   // (C,)
    const float* beta  = (const float*)d_in[3];   // (C,)
    float* out = (float*)d_out;
    float* ws  = (float*)d_ws;

    // ws layout (floats): [part_sum 2048][part_sq 2048][scale 64][shift 64]
    //                     [minv B*C][argminv B*C]  (last two optional)
    float* part_sum = ws;
    float* part_sq  = ws + (size_t)C_ * NB_;
    float* scale    = ws + 2 * (size_t)C_ * NB_;
    float* shift    = scale + C_;
    float* minv = nullptr;
    float* argminv = nullptr;
    const size_t need_min = (2 * (size_t)C_ * NB_ + 2 * C_ + 2 * (size_t)B_ * C_) * sizeof(float);
    if (ws_size >= need_min) {
        minv = shift + C_;
        argminv = minv + (size_t)B_ * C_;
    }

    dim3 g1(NB_, C_);
    hipLaunchKernelGGL(dpq_score, g1, dim3(256), 0, stream,
                       x, cent, out, part_sum, part_sq, minv, argminv);
    hipLaunchKernelGGL(dpq_stats, dim3(1), dim3(64), 0, stream,
                       part_sum, part_sq, gamma, beta, scale, shift);
    hipLaunchKernelGGL(dpq_apply, dim3((B_ * C_) / 256), dim3(256), 0, stream,
                       out, scale, shift, minv, argminv);
    // Third output: centroids passed through unchanged.
    hipMemcpyAsync(out + 2 * (size_t)B_ * C_, cent,
                   (size_t)C_ * K_ * D_ * sizeof(float),
                   hipMemcpyDeviceToDevice, stream);
}

// Round 3
// 142.120 us; speedup vs baseline: 2.0540x; 2.0540x over previous
//
#include <hip/hip_runtime.h>

// Problem constants
#define B_  8192
#define C_  64
#define K_  256
#define D_  64
#define NB_ 32            // b-blocks per channel (8192 / 256)
#define BC_ (B_ * C_)
#define BN_EPS 1e-5

#define WCAP  4096        // tie-referee worklist capacity
#define DELTA 2e-4f       // top-2 gap below which we re-score exactly

typedef _Float16 f16x8 __attribute__((ext_vector_type(8)));
typedef float    f32x4 __attribute__((ext_vector_type(4)));

#define LO_SCALE 2048.0f            // 2^11: keeps lo-parts in f16 normal range
#define LO_INV   4.8828125e-4f      // 2^-11

// XOR swizzle for a [row][128B] LDS plane: breaks the 32-way bank conflict on
// stride-128B ds_read_b128 (G4 / T2). Bijective within each 8-row stripe.
__device__ __forceinline__ int swz(int row, int dbyte) {
    return (row * 128 + dbyte) ^ ((row & 7) << 4);
}

// ---------------------------------------------------------------------------
// Pass 1: MFMA scoring (2-term f16 split, ~2e-7 score error) + top-2 tracking.
// Near-ties (gap < DELTA) are appended to a worklist for exact re-scoring.
// ---------------------------------------------------------------------------
__global__ __launch_bounds__(512) void dpq_mfma(
    const float* __restrict__ x,        // (B, C, D)
    const float* __restrict__ cent,     // (C, K, D)
    const float* __restrict__ gamma,    // (C)
    float* __restrict__ out,            // [codes BC][raw-mse BC][centroids...]
    float* __restrict__ part_sum,       // (C, NB_)
    float* __restrict__ part_sq,        // (C, NB_)
    int* __restrict__ wcount,           // tie worklist counter
    int* __restrict__ worklist)         // tie worklist (WCAP)
{
    __shared__ char lds[65536];         // [0,32K) hi plane, [32K,64K) lo plane
    const int c   = blockIdx.y;
    const int tid = threadIdx.x;
    const float sgn = (gamma[c] < 0.0f) ? -1.0f : 1.0f;   // fold BN-scale sign

    // ---- stage centroids: 512 threads, each converts half a k-row ----
    {
        const int row  = tid >> 1;
        const int half = tid & 1;
        const float* g = cent + ((size_t)c * K_ + row) * D_ + half * 32;
        _Float16 h[32], l[32];
#pragma unroll
        for (int j = 0; j < 32; ++j) {
            float v = g[j] * sgn;
            _Float16 hi = (_Float16)v;
            h[j] = hi;
            l[j] = (_Float16)((v - (float)hi) * LO_SCALE);
        }
#pragma unroll
        for (int q = 0; q < 4; ++q) {
            const int db = half * 64 + q * 16;
            *(f16x8*)(lds +         swz(row, db)) = *(const f16x8*)&h[q * 8];
            *(f16x8*)(lds + 32768 + swz(row, db)) = *(const f16x8*)&l[q * 8];
        }
    }

    // ---- per-wave x fragments: 2 b-tiles x 2 K-steps, hi/lo ----
    const int wid  = tid >> 6;
    const int lane = tid & 63;
    const int col  = lane & 15;     // MFMA B-operand column / A row
    const int grp  = lane >> 4;     // contraction-group
    const int b0   = blockIdx.x * 256 + wid * 32;

    f16x8 bhi[2][2], blo[2][2];
#pragma unroll
    for (int T = 0; T < 2; ++T) {
#pragma unroll
        for (int S = 0; S < 2; ++S) {
            const float* xr = x + ((size_t)(b0 + T * 16 + col) * C_ + c) * D_
                                + S * 32 + grp * 8;
            float4 u0 = *(const float4*)xr;
            float4 u1 = *(const float4*)(xr + 4);
            float v[8] = {u0.x, u0.y, u0.z, u0.w, u1.x, u1.y, u1.z, u1.w};
            f16x8 hh, ll;
#pragma unroll
            for (int j = 0; j < 8; ++j) {
                _Float16 hi = (_Float16)v[j];
                hh[j] = hi;
                ll[j] = (_Float16)((v[j] - (float)hi) * LO_SCALE);
            }
            bhi[T][S] = hh;
            blo[T][S] = ll;
        }
    }

    __syncthreads();

    float best[2]   = {-3.4e38f, -3.4e38f};
    float second[2] = {-3.4e38f, -3.4e38f};
    int   bestk[2]  = {0, 0};
    float accs = 0.0f, accq = 0.0f;

    for (int t = 0; t < 16; ++t) {
        const int krow = t * 16 + col;
        const f16x8 ah0 = *(const f16x8*)(lds +         swz(krow,      grp * 16));
        const f16x8 ah1 = *(const f16x8*)(lds +         swz(krow, 64 + grp * 16));
        const f16x8 al0 = *(const f16x8*)(lds + 32768 + swz(krow,      grp * 16));
        const f16x8 al1 = *(const f16x8*)(lds + 32768 + swz(krow, 64 + grp * 16));
        const int kbase = t * 16 + grp * 4;
#pragma unroll
        for (int T = 0; T < 2; ++T) {
            f32x4 ah = {0.f, 0.f, 0.f, 0.f};
            f32x4 ax = {0.f, 0.f, 0.f, 0.f};
            ah = __builtin_amdgcn_mfma_f32_16x16x32_f16(ah0, bhi[T][0], ah, 0, 0, 0);
            ah = __builtin_amdgcn_mfma_f32_16x16x32_f16(ah1, bhi[T][1], ah, 0, 0, 0);
            ax = __builtin_amdgcn_mfma_f32_16x16x32_f16(ah0, blo[T][0], ax, 0, 0, 0);
            ax = __builtin_amdgcn_mfma_f32_16x16x32_f16(ah1, blo[T][1], ax, 0, 0, 0);
            ax = __builtin_amdgcn_mfma_f32_16x16x32_f16(al0, bhi[T][0], ax, 0, 0, 0);
            ax = __builtin_amdgcn_mfma_f32_16x16x32_f16(al1, bhi[T][1], ax, 0, 0, 0);
#pragma unroll
            for (int j = 0; j < 4; ++j) {
                const float r = fmaf(ax[j], LO_INV, ah[j]);
                accs += r;
                accq = fmaf(r, r, accq);
                // branchless top-2: old best demotes to second when beaten
                second[T] = fmaxf(second[T], fminf(r, best[T]));
                if (r > best[T]) { best[T] = r; bestk[T] = kbase + j; }
            }
        }
    }

    // ---- cross-lane top-2/argmax reduce (same-col lanes differ in bits 4,5) --
#pragma unroll
    for (int T = 0; T < 2; ++T) {
        float bv = best[T], sv = second[T];
        int   bk = bestk[T];
#pragma unroll
        for (int m = 16; m <= 32; m <<= 1) {
            const float ov = __shfl_xor(bv, m);
            const int   ok = __shfl_xor(bk, m);
            const float os = __shfl_xor(sv, m);
            const float hi = fmaxf(bv, ov);
            const float lo = fminf(bv, ov);
            sv = fmaxf(fmaxf(sv, os), lo);
            if (ov > bv || (ov == bv && ok < bk)) bk = ok;
            bv = hi;
        }
        if (grp == 0) {   // lanes 0..15 hold cols 0..15
            const size_t idx = (size_t)(b0 + T * 16 + col) * C_ + c;
            out[idx] = (float)bk;                 // code (maybe refereed later)
            out[(size_t)BC_ + idx] = bv;          // raw max (affine later)
            if (bv - sv < DELTA && worklist) {    // near-tie -> exact re-score
                const int slot = atomicAdd(wcount, 1);
                if (slot < WCAP) worklist[slot] = (int)idx;
            }
        }
    }

    // ---- channel-stats reduce: wave shuffle -> LDS (reused) -> partials ----
#pragma unroll
    for (int m = 1; m <= 32; m <<= 1) {
        accs += __shfl_xor(accs, m);
        accq += __shfl_xor(accq, m);
    }
    __syncthreads();                   // centroid planes dead; reuse LDS
    float* red = (float*)lds;
    if (lane == 0) { red[wid] = accs; red[8 + wid] = accq; }
    __syncthreads();
    if (tid == 0) {
        float s = 0.f, q = 0.f;
#pragma unroll
        for (int w = 0; w < 8; ++w) { s += red[w]; q += red[8 + w]; }
        part_sum[c * NB_ + blockIdx.x] = s;
        part_sq [c * NB_ + blockIdx.x] = q;
    }
}

// ---------------------------------------------------------------------------
// Referee: exact fp64 re-scoring of near-tie pairs. One wave per entry.
// Overwrites codes + raw max with the exact argmax/max (first-occurrence ties).
// ---------------------------------------------------------------------------
__global__ __launch_bounds__(64) void dpq_referee(
    const float* __restrict__ x,
    const float* __restrict__ cent,
    const float* __restrict__ gamma,
    const int* __restrict__ wcount,
    const int* __restrict__ worklist,
    float* __restrict__ out)
{
    int n = *wcount;
    if (n > WCAP) n = WCAP;
    const int lane = threadIdx.x;
    for (int i = blockIdx.x; i < n; i += gridDim.x) {
        const int idx = worklist[i];
        const int c = idx & (C_ - 1);
        const int b = idx >> 6;                      // C_ == 64
        const double sgn = (gamma[c] < 0.0f) ? -1.0 : 1.0;
        const float* xr = x + ((size_t)b * C_ + c) * D_;
        const float* cb = cent + (size_t)c * K_ * D_;
        double bv = -1.0e300;
        int bk = 0;
        for (int kk = 0; kk < 4; ++kk) {
            const int k = kk * 64 + lane;            // ascending per lane
            const float* cr = cb + (size_t)k * D_;
            double s = 0.0;
#pragma unroll
            for (int d = 0; d < D_; ++d)
                s += (double)xr[d] * (double)cr[d];
            s *= sgn;
            if (s > bv) { bv = s; bk = k; }
        }
#pragma unroll
        for (int m = 1; m <= 32; m <<= 1) {
            const double ov = __shfl_xor(bv, m);
            const int   ok = __shfl_xor(bk, m);
            if (ov > bv || (ov == bv && ok < bk)) { bv = ov; bk = ok; }
        }
        if (lane == 0) {
            out[idx] = (float)bk;
            out[(size_t)BC_ + idx] = (float)bv;
        }
    }
}

// ---------------------------------------------------------------------------
// Per-channel BN stats on the sign-folded scores r' = sgn*r.
// ---------------------------------------------------------------------------
__global__ void dpq_stats(
    const float* __restrict__ part_sum,
    const float* __restrict__ part_sq,
    const float* __restrict__ gamma,
    const float* __restrict__ beta,
    float* __restrict__ scale_out,
    float* __restrict__ shift_out)
{
    const int c = threadIdx.x;
    if (c >= C_) return;
    double s = 0.0, q = 0.0;
    for (int i = 0; i < NB_; ++i) {
        s += (double)part_sum[c * NB_ + i];
        q += (double)part_sq [c * NB_ + i];
    }
    const double n    = (double)B_ * (double)K_;
    const double mean = s / n;
    const double var  = q / n - mean * mean;      // biased, matches reference
    const double sc   = fabs((double)gamma[c]) / sqrt(var + BN_EPS);
    scale_out[c] = (float)sc;
    shift_out[c] = (float)((double)beta[c] - mean * sc);
}

// ---------------------------------------------------------------------------
// Apply per-channel affine to the stored raw max (in-place in d_out).
// gamma==0 degenerates to constant output: argmax 0, value beta.
// ---------------------------------------------------------------------------
__global__ __launch_bounds__(256) void dpq_apply(
    float* __restrict__ out,
    const float* __restrict__ scale,
    const float* __restrict__ shift)
{
    const int idx = blockIdx.x * 256 + threadIdx.x;   // over B*C, c fastest
    const int c = idx & (C_ - 1);
    const float sc = scale[c];
    const float sh = shift[c];
    if (sc == 0.0f) {
        out[idx] = 0.0f;
        out[(size_t)BC_ + idx] = sh;
    } else {
        out[(size_t)BC_ + idx] = fmaf(out[(size_t)BC_ + idx], sc, sh);
    }
}

// ---------------------------------------------------------------------------
extern "C" void kernel_launch(void* const* d_in, const int* in_sizes, int n_in,
                              void* d_out, int out_size, void* d_ws, size_t ws_size,
                              hipStream_t stream)
{
    const float* x     = (const float*)d_in[0];
    const float* cent  = (const float*)d_in[1];
    const float* gamma = (const float*)d_in[2];
    const float* beta  = (const float*)d_in[3];
    float* out = (float*)d_out;
    float* ws  = (float*)d_ws;

    // ws layout (4-byte units):
    // [0,2048) part_sum | [2048,4096) part_sq | [4096,4160) scale
    // [4160,4224) shift | [4224] wcount | [4225, 4225+WCAP) worklist
    float* part_sum = ws;
    float* part_sq  = ws + 2048;
    float* scale    = ws + 4096;
    float* shift    = ws + 4160;
    int*   wcount   = (int*)(ws + 4224);
    int*   worklist = (int*)(ws + 4225);
    const size_t need = (size_t)(4225 + WCAP) * 4;
    if (ws_size < need) { wcount = nullptr; worklist = nullptr; }

    if (wcount)
        hipMemsetAsync(wcount, 0, sizeof(int), stream);

    dim3 g1(B_ / 256, C_);   // (32, 64)
    hipLaunchKernelGGL(dpq_mfma, g1, dim3(512), 0, stream,
                       x, cent, gamma, out, part_sum, part_sq, wcount, worklist);
    if (wcount)
        hipLaunchKernelGGL(dpq_referee, dim3(128), dim3(64), 0, stream,
                           x, cent, gamma, wcount, worklist, out);
    hipLaunchKernelGGL(dpq_stats, dim3(1), dim3(64), 0, stream,
                       part_sum, part_sq, gamma, beta, scale, shift);
    hipLaunchKernelGGL(dpq_apply, dim3(BC_ / 256), dim3(256), 0, stream,
                       out, scale, shift);
    hipMemcpyAsync(out + 2 * (size_t)BC_, cent,
                   (size_t)C_ * K_ * D_ * sizeof(float),
                   hipMemcpyDeviceToDevice, stream);
}

// Round 4
// 101.018 us; speedup vs baseline: 2.8897x; 1.4069x over previous
//
#include <hip/hip_runtime.h>

// Problem constants
#define B_  8192
#define C_  64
#define K_  256
#define D_  64
#define NBT 2                 // b-tiles per block
#define GX  (B_ / (256 * NBT))// 16 blocks along b
#define BC_ (B_ * C_)
#define BN_EPS 1e-5

#define WCAP_C 1024           // per-channel referee list capacity
#define DELTA  2.5e-3f        // top-2 gap flag band (~5.5 sigma of pair err)

typedef _Float16 f16x8 __attribute__((ext_vector_type(8)));
typedef float    f32x4 __attribute__((ext_vector_type(4)));

// XOR swizzle for [row][128B] f16 plane: kills 32-way conflict on ds_read_b128.
__device__ __forceinline__ int swz(int row, int dbyte) {
    return (row * 128 + dbyte) ^ ((row & 7) << 4);
}

// ---------------------------------------------------------------------------
// Pass 1: single-pass f16 MFMA scoring + exact-top-2 tracking.
// Block 512 thr, 32 KiB LDS (f16 centroid plane), loops NBT b-tiles of 256.
// Near-ties (gap < DELTA) pushed to per-channel worklist for fp64 referee.
// ---------------------------------------------------------------------------
__global__ __launch_bounds__(512, 6) void dpq_mfma(
    const float* __restrict__ x,        // (B, C, D)
    const float* __restrict__ cent,     // (C, K, D)
    const float* __restrict__ gamma,    // (C)
    float* __restrict__ out,            // [codes BC][raw mse BC][centroids]
    float* __restrict__ part_sum,       // (C, GX)
    float* __restrict__ part_sq,        // (C, GX)
    int* __restrict__ wcount,           // (C)
    int* __restrict__ worklist)         // (C, WCAP_C) stores b
{
    __shared__ char lds[32768];
    const int c   = blockIdx.y;
    const int tid = threadIdx.x;
    const float sgn = (gamma[c] < 0.0f) ? -1.0f : 1.0f;   // fold BN sign

    // ---- stage centroids as sign-folded f16 (chunked: low reg pressure) ----
    {
        const int row = tid >> 1, half = tid & 1;
        const float* g = cent + ((size_t)c * K_ + row) * D_ + half * 32;
#pragma unroll
        for (int q = 0; q < 4; ++q) {
            float4 u0 = *(const float4*)(g + q * 8);
            float4 u1 = *(const float4*)(g + q * 8 + 4);
            f16x8 h;
            h[0] = (_Float16)(u0.x * sgn); h[1] = (_Float16)(u0.y * sgn);
            h[2] = (_Float16)(u0.z * sgn); h[3] = (_Float16)(u0.w * sgn);
            h[4] = (_Float16)(u1.x * sgn); h[5] = (_Float16)(u1.y * sgn);
            h[6] = (_Float16)(u1.z * sgn); h[7] = (_Float16)(u1.w * sgn);
            *(f16x8*)(lds + swz(row, half * 64 + q * 16)) = h;
        }
    }

    const int wid = tid >> 6, lane = tid & 63;
    const int col = lane & 15, grp = lane >> 4;

    float accs = 0.0f, accq = 0.0f;
    bool first = true;

    for (int bt = 0; bt < NBT; ++bt) {
        const int b0 = (blockIdx.x * NBT + bt) * 256 + wid * 32;

        // x fragments: 2 b-subtiles x 2 d-halves
        f16x8 xf[2][2];
#pragma unroll
        for (int T = 0; T < 2; ++T)
#pragma unroll
            for (int S = 0; S < 2; ++S) {
                const float* xr = x + ((size_t)(b0 + T * 16 + col) * C_ + c) * D_
                                    + S * 32 + grp * 8;
                float4 u0 = *(const float4*)xr;
                float4 u1 = *(const float4*)(xr + 4);
                f16x8 h;
                h[0] = (_Float16)u0.x; h[1] = (_Float16)u0.y;
                h[2] = (_Float16)u0.z; h[3] = (_Float16)u0.w;
                h[4] = (_Float16)u1.x; h[5] = (_Float16)u1.y;
                h[6] = (_Float16)u1.z; h[7] = (_Float16)u1.w;
                xf[T][S] = h;
            }
        if (first) { __syncthreads(); first = false; }   // staging done

        float best[2] = {-3.4e38f, -3.4e38f};
        float sec [2] = {-3.4e38f, -3.4e38f};
        int   bk_ [2] = {0, 0};

#pragma unroll 4
        for (int t = 0; t < 16; ++t) {
            const f16x8 a0 = *(const f16x8*)(lds + swz(t * 16 + col,      grp * 16));
            const f16x8 a1 = *(const f16x8*)(lds + swz(t * 16 + col, 64 + grp * 16));
            const int kb = t * 16 + grp * 4;
#pragma unroll
            for (int T = 0; T < 2; ++T) {
                f32x4 acc = {0.f, 0.f, 0.f, 0.f};
                acc = __builtin_amdgcn_mfma_f32_16x16x32_f16(a0, xf[T][0], acc, 0, 0, 0);
                acc = __builtin_amdgcn_mfma_f32_16x16x32_f16(a1, xf[T][1], acc, 0, 0, 0);
#pragma unroll
                for (int j = 0; j < 4; ++j) {
                    const float r = acc[j];
                    accs += r;
                    accq = fmaf(r, r, accq);
                    const bool gt = r > best[T];
                    sec[T]  = __builtin_amdgcn_fmed3f(r, best[T], sec[T]); // new 2nd
                    best[T] = fmaxf(best[T], r);
                    bk_[T]  = gt ? kb + j : bk_[T];
                }
            }
        }

        // cross-lane top-2/argmax merge (same-col lanes differ in bits 4,5)
#pragma unroll
        for (int T = 0; T < 2; ++T) {
            float bv = best[T], sv = sec[T];
            int   bk = bk_[T];
#pragma unroll
            for (int m = 16; m <= 32; m <<= 1) {
                const float ov = __shfl_xor(bv, m);
                const int   ok = __shfl_xor(bk, m);
                const float os = __shfl_xor(sv, m);
                sv = fmaxf(fmaxf(sv, os), fminf(bv, ov));
                if (ov > bv || (ov == bv && ok < bk)) bk = ok;
                bv = fmaxf(bv, ov);
            }
            if (grp == 0) {
                const int b = b0 + T * 16 + col;
                const size_t idx = (size_t)b * C_ + c;
                out[idx] = (float)bk;                  // code (maybe refereed)
                out[(size_t)BC_ + idx] = bv;           // raw max (affine later)
                if (bv - sv < DELTA && worklist) {
                    const int slot = atomicAdd(&wcount[c], 1);
                    if (slot < WCAP_C) worklist[c * WCAP_C + slot] = b;
                }
            }
        }
    }

    // ---- channel sum / sumsq block reduction ----
#pragma unroll
    for (int m = 1; m <= 32; m <<= 1) {
        accs += __shfl_xor(accs, m);
        accq += __shfl_xor(accq, m);
    }
    __syncthreads();                    // plane dead; reuse LDS
    float* red = (float*)lds;
    if (lane == 0) { red[wid] = accs; red[8 + wid] = accq; }
    __syncthreads();
    if (tid == 0) {
        float s = 0.f, q = 0.f;
#pragma unroll
        for (int w = 0; w < 8; ++w) { s += red[w]; q += red[8 + w]; }
        part_sum[c * GX + blockIdx.x] = s;
        part_sq [c * GX + blockIdx.x] = q;
    }
}

// ---------------------------------------------------------------------------
// Referee: exact fp64 re-score of flagged pairs, channel-bucketed.
// grid (64, 8): block (c, s) stages channel c's centroids (f32, bank-swizzled)
// in 64 KiB LDS once; each WAVE takes one entry (lane = 4 k's), fp64 dot.
// ---------------------------------------------------------------------------
__global__ __launch_bounds__(256) void dpq_referee(
    const float* __restrict__ x,
    const float* __restrict__ cent,
    const float* __restrict__ gamma,
    const int* __restrict__ wcount,
    const int* __restrict__ worklist,
    float* __restrict__ out)
{
    __shared__ float cl[K_ * D_];       // 64 KiB exact centroids
    const int c = blockIdx.x;
    int n = wcount[c];
    if (n > WCAP_C) n = WCAP_C;
    if (n == 0) return;
    const int t = threadIdx.x;          // 0..255 = k row to stage
    const float sgnf = (gamma[c] < 0.0f) ? -1.0f : 1.0f;

    // stage row t with d-swizzle (d ^ (k&31)) -> conflict-free lane reads
    {
        const float* g = cent + ((size_t)c * K_ + t) * D_;
#pragma unroll 8
        for (int d = 0; d < D_; ++d)
            cl[t * D_ + (d ^ (t & 31))] = g[d];
    }
    __syncthreads();

    const int wid = t >> 6, lane = t & 63;
    for (int i = blockIdx.y * 4 + wid; i < n; i += gridDim.y * 4) {
        const int b = worklist[c * WCAP_C + i];
        const float* xr = x + ((size_t)b * C_ + c) * D_;
        double bv = -1.0e300;
        int bk = 0;
#pragma unroll
        for (int q = 0; q < 4; ++q) {
            const int k = q * 64 + lane;            // ascending per lane
            const int sw = k & 31;
            double s = 0.0;
#pragma unroll 8
            for (int d = 0; d < D_; ++d)
                s += (double)xr[d] * (double)cl[k * D_ + (d ^ sw)];
            s *= (double)sgnf;
            if (s > bv) { bv = s; bk = k; }
        }
#pragma unroll
        for (int m = 1; m <= 32; m <<= 1) {
            const double ov = __shfl_xor(bv, m);
            const int   ok = __shfl_xor(bk, m);
            if (ov > bv || (ov == bv && ok < bk)) { bv = ov; bk = ok; }
        }
        if (lane == 0) {
            const size_t idx = (size_t)b * C_ + c;
            out[idx] = (float)bk;
            out[(size_t)BC_ + idx] = (float)bv;
        }
    }
}

// ---------------------------------------------------------------------------
// Per-channel BN stats on sign-folded scores.
// ---------------------------------------------------------------------------
__global__ void dpq_stats(
    const float* __restrict__ part_sum,
    const float* __restrict__ part_sq,
    const float* __restrict__ gamma,
    const float* __restrict__ beta,
    float* __restrict__ scale_out,
    float* __restrict__ shift_out)
{
    const int c = threadIdx.x;
    if (c >= C_) return;
    double s = 0.0, q = 0.0;
    for (int i = 0; i < GX; ++i) {
        s += (double)part_sum[c * GX + i];
        q += (double)part_sq [c * GX + i];
    }
    const double n    = (double)B_ * (double)K_;
    const double mean = s / n;
    const double var  = q / n - mean * mean;      // biased, matches reference
    const double sc   = fabs((double)gamma[c]) / sqrt(var + BN_EPS);
    scale_out[c] = (float)sc;
    shift_out[c] = (float)((double)beta[c] - mean * sc);
}

// ---------------------------------------------------------------------------
// Apply per-channel affine to stored raw max. gamma==0 -> constant channel.
// ---------------------------------------------------------------------------
__global__ __launch_bounds__(256) void dpq_apply(
    float* __restrict__ out,
    const float* __restrict__ scale,
    const float* __restrict__ shift)
{
    const int idx = blockIdx.x * 256 + threadIdx.x;   // over B*C, c fastest
    const int c = idx & (C_ - 1);
    const float sc = scale[c];
    const float sh = shift[c];
    if (sc == 0.0f) {
        out[idx] = 0.0f;
        out[(size_t)BC_ + idx] = sh;
    } else {
        out[(size_t)BC_ + idx] = fmaf(out[(size_t)BC_ + idx], sc, sh);
    }
}

// ---------------------------------------------------------------------------
extern "C" void kernel_launch(void* const* d_in, const int* in_sizes, int n_in,
                              void* d_out, int out_size, void* d_ws, size_t ws_size,
                              hipStream_t stream)
{
    const float* x     = (const float*)d_in[0];
    const float* cent  = (const float*)d_in[1];
    const float* gamma = (const float*)d_in[2];
    const float* beta  = (const float*)d_in[3];
    float* out = (float*)d_out;
    float* ws  = (float*)d_ws;

    // ws layout (4B units): [0,1024) part_sum | [1024,2048) part_sq
    // [2048,2112) scale | [2112,2176) shift | [2176,2240) wcount[64]
    // [2240, 2240+64*WCAP_C) worklist
    float* part_sum = ws;
    float* part_sq  = ws + 1024;
    float* scale    = ws + 2048;
    float* shift    = ws + 2112;
    int*   wcount   = (int*)(ws + 2176);
    int*   worklist = (int*)(ws + 2240);
    const size_t need = (size_t)(2240 + C_ * WCAP_C) * 4;
    if (ws_size < need) { wcount = nullptr; worklist = nullptr; }

    if (wcount)
        hipMemsetAsync(wcount, 0, C_ * sizeof(int), stream);

    dim3 g1(GX, C_);   // (16, 64)
    hipLaunchKernelGGL(dpq_mfma, g1, dim3(512), 0, stream,
                       x, cent, gamma, out, part_sum, part_sq, wcount, worklist);
    if (wcount)
        hipLaunchKernelGGL(dpq_referee, dim3(C_, 8), dim3(256), 0, stream,
                           x, cent, gamma, wcount, worklist, out);
    hipLaunchKernelGGL(dpq_stats, dim3(1), dim3(64), 0, stream,
                       part_sum, part_sq, gamma, beta, scale, shift);
    hipLaunchKernelGGL(dpq_apply, dim3(BC_ / 256), dim3(256), 0, stream,
                       out, scale, shift);
    hipMemcpyAsync(out + 2 * (size_t)BC_, cent,
                   (size_t)C_ * K_ * D_ * sizeof(float),
                   hipMemcpyDeviceToDevice, stream);
}